// Round 8
// baseline (306.677 us; speedup 1.0000x reference)
//
#include <hip/hip_runtime.h>
#include <hip/hip_bf16.h>
#include <cstdint>

// Toy MultiHeadAttention: B=2, L=2048, D=1024, H=16, HD=64, causal, eval (no dropout)
// Pipeline: fp32->bf16 converts; QKV GEMM (bf16 MFMA) with Q/K/Vt scatter epilogue;
// causal flash attention (swapped-QK^T; defer-max softmax (T13), cvt_pk packing,
// 2-tile pairing for ILP, zero-shuffle P->PV via 16x16x16 B-frag); out GEMM + bias.

typedef __attribute__((ext_vector_type(8))) short sh8;    // 8 bf16 (4 VGPRs) for 16x16x32
typedef __attribute__((ext_vector_type(4))) short sh4;    // 4 bf16 (2 VGPRs) for 16x16x16
typedef __attribute__((ext_vector_type(4))) float f32x4;  // MFMA C/D frag

__device__ __forceinline__ unsigned short f2b(float f) {  // fp32 -> bf16 RNE
  unsigned int u = __float_as_uint(f);
  u += 0x7FFFu + ((u >> 16) & 1u);
  return (unsigned short)(u >> 16);
}

__device__ __forceinline__ unsigned int pack2(float lo, float hi) {  // 2xbf16 via HW cvt_pk
  unsigned int r;
  asm("v_cvt_pk_bf16_f32 %0, %1, %2" : "=v"(r) : "v"(lo), "v"(hi));
  return r;
}

__device__ __forceinline__ f32x4 mfma16x16x16(sh4 a, sh4 b, f32x4 c) {
#if __has_builtin(__builtin_amdgcn_mfma_f32_16x16x16bf16_1k)
  return __builtin_amdgcn_mfma_f32_16x16x16bf16_1k(a, b, c, 0, 0, 0);
#else
  asm volatile("v_mfma_f32_16x16x16_bf16 %0, %1, %2, %0" : "+v"(c) : "v"(a), "v"(b));
  return c;
#endif
}

__device__ __forceinline__ void gload_lds16(const void* g, void* l) {
  __builtin_amdgcn_global_load_lds((__attribute__((address_space(1))) void*)g,
                                   (__attribute__((address_space(3))) void*)l,
                                   16, 0, 0);
}

// ---------------- fp32 -> bf16 convert (vectorized) ----------------
__global__ __launch_bounds__(256) void k_cvt(const float* __restrict__ in,
                                             unsigned short* __restrict__ out, int n) {
  int idx = (blockIdx.x * 256 + threadIdx.x) * 4;
  if (idx >= n) return;
  float4 v = *(const float4*)&in[idx];
  union { unsigned short u[4]; uint2 w; } r;
  r.u[0] = f2b(v.x); r.u[1] = f2b(v.y); r.u[2] = f2b(v.z); r.u[3] = f2b(v.w);
  *(uint2*)&out[idx] = r.w;
}

// ---------------- shared GEMM core: C[128x128] = A[M,K] * B[N,K]^T ----------------
__device__ __forceinline__ void gemm_bt_core(
    const unsigned short* __restrict__ A,   // [M][K] bf16 row-major
    const unsigned short* __restrict__ B,   // [N][K] bf16 row-major
    int K, int m0, int n0,
    unsigned short* ldsA, unsigned short* ldsB,
    f32x4 acc[4][4]) {
  const int tid  = threadIdx.x;
  const int wv   = tid >> 6;
  const int lane = tid & 63;
  const int wm = (wv >> 1) << 6;
  const int wn = (wv & 1) << 6;
  const int sr = (wv << 5) + (lane >> 3);
  const int sc = (lane & 7) << 3;
  const int fr = lane & 15;
  const int fk = (lane >> 4) << 3;

  for (int k0 = 0; k0 < K; k0 += 64) {
#pragma unroll
    for (int t = 0; t < 4; ++t) {
      int r = sr + (t << 3);
      gload_lds16(&A[(size_t)(m0 + r) * K + k0 + sc], &ldsA[r * 64 + sc]);
      gload_lds16(&B[(size_t)(n0 + r) * K + k0 + sc], &ldsB[r * 64 + sc]);
    }
    __syncthreads();
#pragma unroll
    for (int ks = 0; ks < 2; ++ks) {
      sh8 af[4], bf[4];
#pragma unroll
      for (int mt = 0; mt < 4; ++mt)
        af[mt] = *(const sh8*)&ldsA[(wm + mt * 16 + fr) * 64 + ks * 32 + fk];
#pragma unroll
      for (int nt = 0; nt < 4; ++nt)
        bf[nt] = *(const sh8*)&ldsB[(wn + nt * 16 + fr) * 64 + ks * 32 + fk];
#pragma unroll
      for (int mt = 0; mt < 4; ++mt)
#pragma unroll
        for (int nt = 0; nt < 4; ++nt)
          acc[mt][nt] = __builtin_amdgcn_mfma_f32_16x16x32_bf16(af[mt], bf[nt], acc[mt][nt], 0, 0, 0);
    }
    __syncthreads();
  }
}

// ---------------- QKV projection + scatter ----------------
__global__ __launch_bounds__(256) void k_qkv_gemm(
    const unsigned short* __restrict__ xb, const unsigned short* __restrict__ wq,
    unsigned short* __restrict__ Q, unsigned short* __restrict__ Kc,
    unsigned short* __restrict__ Vt) {
  __shared__ __align__(16) unsigned short lds[2 * 128 * 64];
  f32x4 acc[4][4];
  const f32x4 fz = {0.f, 0.f, 0.f, 0.f};
#pragma unroll
  for (int i = 0; i < 4; ++i)
#pragma unroll
    for (int j = 0; j < 4; ++j) acc[i][j] = fz;

  const int m0 = blockIdx.x * 128, n0 = blockIdx.y * 128;
  gemm_bt_core(xb, wq, 1024, m0, n0, lds, lds + 128 * 64, acc);

  const int tid = threadIdx.x, wv = tid >> 6, lane = tid & 63;
  const int wm = (wv >> 1) << 6, wn = (wv & 1) << 6;
  const int r4 = (lane >> 4) << 2, fr = lane & 15;
#pragma unroll
  for (int mt = 0; mt < 4; ++mt)
#pragma unroll
    for (int nt = 0; nt < 4; ++nt)
#pragma unroll
      for (int i = 0; i < 4; ++i) {
        int row = m0 + wm + mt * 16 + r4 + i;   // m in [0,4096)
        int col = n0 + wn + nt * 16 + fr;       // n in [0,3072)
        float v = acc[mt][nt][i];
        int b = row >> 11, lq = row & 2047;
        int which = col >> 10, rem = col & 1023;
        int h = rem >> 6, hd = rem & 63;
        size_t bh = (size_t)(b * 16 + h);
        if (which == 0)      Q [(bh * 2048 + lq) * 64 + hd] = f2b(v * 0.125f);
        else if (which == 1) Kc[(bh * 2048 + lq) * 64 + hd] = f2b(v);
        else                 Vt[(bh * 64 + hd) * 2048 + lq] = f2b(v);
      }
}

// ---------------- causal flash attention ----------------
// grid: 1024 blocks x 256 thr. blockIdx = sb*32 + bh; wave wv owns strip 4*sb+wv
// (adjacent strips -> near-uniform per-block work; all blocks resident).
// Swapped QK: s = mfma(K, Q): lane(g,fr) holds kv = kvb + 16t + 4g + i, q = qw + fr.
// T13 defer-max: common path has NO cross-lane ops (per-lane pmax + __all check);
// l accumulates per-lane, reduced once at the end. P packs via v_cvt_pk_bf16_f32
// straight into the 16x16x16 PV B-frag (k = 4g + j). 2 kv-tiles per iteration (ILP).
struct TileR { f32x4 s0, s1; sh4 vf[4][2]; float pmax; };

__device__ __forceinline__ TileR tile_qk(
    const unsigned short* __restrict__ Kb, const unsigned short* __restrict__ Vb,
    int kvb, const sh8* qf, bool diag, int qw, int fr, int r4, int fk) {
  TileR t;
  const f32x4 fz = {0.f, 0.f, 0.f, 0.f};
  t.s0 = fz; t.s1 = fz;
  sh8 kf0[2], kf1[2];
#pragma unroll
  for (int ks = 0; ks < 2; ++ks) {
    kf0[ks] = *(const sh8*)&Kb[(size_t)(kvb + fr) * 64 + ks * 32 + fk];
    kf1[ks] = *(const sh8*)&Kb[(size_t)(kvb + 16 + fr) * 64 + ks * 32 + fk];
  }
#pragma unroll
  for (int ks = 0; ks < 2; ++ks) {
    t.s0 = __builtin_amdgcn_mfma_f32_16x16x32_bf16(kf0[ks], qf[ks], t.s0, 0, 0, 0);
    t.s1 = __builtin_amdgcn_mfma_f32_16x16x32_bf16(kf1[ks], qf[ks], t.s1, 0, 0, 0);
  }
  // V frags (A-operand of 16x16x16): row d = fr, k = 4g + j
#pragma unroll
  for (int hb = 0; hb < 4; ++hb)
#pragma unroll
    for (int tt = 0; tt < 2; ++tt)
      t.vf[hb][tt] = *(const sh4*)&Vb[(size_t)(hb * 16 + fr) * 2048 + kvb + tt * 16 + r4];
  if (diag) {
#pragma unroll
    for (int i = 0; i < 4; ++i) {
      if (kvb + r4 + i > qw + fr)      t.s0[i] = -1e30f;
      if (kvb + 16 + r4 + i > qw + fr) t.s1[i] = -1e30f;
    }
  }
  t.pmax = fmaxf(fmaxf(fmaxf(t.s0[0], t.s0[1]), fmaxf(t.s0[2], t.s0[3])),
                 fmaxf(fmaxf(t.s1[0], t.s1[1]), fmaxf(t.s1[2], t.s1[3])));
  return t;
}

__device__ __forceinline__ void defer_chk(float pm, float& m_i, float& lp, f32x4 o[4]) {
  if (!__all(pm - m_i <= 8.0f)) {   // rare: full row-max reduce + rescale
    float rm = fmaxf(pm, __shfl_xor(pm, 16, 64));
    rm = fmaxf(rm, __shfl_xor(rm, 32, 64));
    const float mn = fmaxf(m_i, rm);
    const float sc = __expf(m_i - mn);
    m_i = mn;
    lp *= sc;
#pragma unroll
    for (int hb = 0; hb < 4; ++hb)
#pragma unroll
      for (int i = 0; i < 4; ++i) o[hb][i] *= sc;
  }
}

__device__ __forceinline__ void tile_pv(const TileR& t, float m_i, float& lp, f32x4 o[4]) {
  float p[8];
#pragma unroll
  for (int i = 0; i < 4; ++i) {
    p[i]     = __expf(t.s0[i] - m_i);
    p[4 + i] = __expf(t.s1[i] - m_i);
  }
  lp += ((p[0] + p[1]) + (p[2] + p[3])) + ((p[4] + p[5]) + (p[6] + p[7]));
  union { unsigned int w[2]; sh4 v; } a0, a1;
  a0.w[0] = pack2(p[0], p[1]); a0.w[1] = pack2(p[2], p[3]);
  a1.w[0] = pack2(p[4], p[5]); a1.w[1] = pack2(p[6], p[7]);
#pragma unroll
  for (int hb = 0; hb < 4; ++hb) {
    o[hb] = mfma16x16x16(t.vf[hb][0], a0.v, o[hb]);
    o[hb] = mfma16x16x16(t.vf[hb][1], a1.v, o[hb]);
  }
}

__global__ __launch_bounds__(256, 3) void k_attn(
    const unsigned short* __restrict__ Q, const unsigned short* __restrict__ Kc,
    const unsigned short* __restrict__ Vt, unsigned short* __restrict__ attn) {
  const int bh = blockIdx.x & 31;
  const int sb = blockIdx.x >> 5;               // 0..31
  const int wv = threadIdx.x >> 6, lane = threadIdx.x & 63;
  const int strip = (sb << 2) + wv;             // 0..127 (adjacent in block)
  const int qw = strip << 4;
  const int b = bh >> 4, h = bh & 15;
  const unsigned short* Qb = Q  + (size_t)bh * 2048 * 64;
  const unsigned short* Kb = Kc + (size_t)bh * 2048 * 64;
  const unsigned short* Vb = Vt + (size_t)bh * 64 * 2048;
  const int fr = lane & 15, g = lane >> 4;
  const int fk = g << 3, r4 = g << 2;
  const f32x4 fz = {0.f, 0.f, 0.f, 0.f};

  sh8 qf[2];
#pragma unroll
  for (int ks = 0; ks < 2; ++ks)
    qf[ks] = *(const sh8*)&Qb[(size_t)(qw + fr) * 64 + ks * 32 + fk];

  f32x4 o[4];
#pragma unroll
  for (int i = 0; i < 4; ++i) o[i] = fz;
  float m_i = -1e30f, lp = 0.f;

  const int nj = (qw + 47) >> 5;                // 32-kv tiles up to the diagonal
  int j = 0;
  for (; j + 1 < nj; j += 2) {
    TileR ta = tile_qk(Kb, Vb, j << 5, qf, false, qw, fr, r4, fk);
    TileR tb = tile_qk(Kb, Vb, (j + 1) << 5, qf, (j + 2) == nj, qw, fr, r4, fk);
    defer_chk(fmaxf(ta.pmax, tb.pmax), m_i, lp, o);
    tile_pv(ta, m_i, lp, o);
    tile_pv(tb, m_i, lp, o);
  }
  if (j < nj) {
    TileR ta = tile_qk(Kb, Vb, j << 5, qf, true, qw, fr, r4, fk);
    defer_chk(ta.pmax, m_i, lp, o);
    tile_pv(ta, m_i, lp, o);
  }

  float l = lp;                                  // row sum: reduce across g once
  l += __shfl_xor(l, 16, 64);
  l += __shfl_xor(l, 32, 64);
  const float inv = 1.0f / l;
  // o layout: col = q = fr (lane), row = d = hb*16 + r4 + i -> pack i-pairs, b32 stores
  const size_t base = ((size_t)(b * 2048 + qw + fr)) * 1024 + h * 64;
#pragma unroll
  for (int hb = 0; hb < 4; ++hb)
#pragma unroll
    for (int i2 = 0; i2 < 2; ++i2) {
      unsigned int pw = pack2(o[hb][2 * i2] * inv, o[hb][2 * i2 + 1] * inv);
      *(unsigned int*)&attn[base + hb * 16 + r4 + 2 * i2] = pw;
    }
}

// ---------------- output projection + bias (fp32 out) ----------------
__global__ __launch_bounds__(256) void k_out_gemm(
    const unsigned short* __restrict__ attn, const unsigned short* __restrict__ wo,
    const float* __restrict__ bias, float* __restrict__ out) {
  __shared__ __align__(16) unsigned short lds[2 * 128 * 64];
  f32x4 acc[4][4];
  const f32x4 fz = {0.f, 0.f, 0.f, 0.f};
#pragma unroll
  for (int i = 0; i < 4; ++i)
#pragma unroll
    for (int j = 0; j < 4; ++j) acc[i][j] = fz;

  const int m0 = blockIdx.x * 128, n0 = blockIdx.y * 128;
  gemm_bt_core(attn, wo, 1024, m0, n0, lds, lds + 128 * 64, acc);

  const int tid = threadIdx.x, wv = tid >> 6, lane = tid & 63;
  const int wm = (wv >> 1) << 6, wn = (wv & 1) << 6;
  const int r4 = (lane >> 4) << 2, fr = lane & 15;
#pragma unroll
  for (int mt = 0; mt < 4; ++mt)
#pragma unroll
    for (int nt = 0; nt < 4; ++nt)
#pragma unroll
      for (int i = 0; i < 4; ++i) {
        int row = m0 + wm + mt * 16 + r4 + i;
        int col = n0 + wn + nt * 16 + fr;
        out[(size_t)row * 1024 + col] = acc[mt][nt][i] + bias[col];
      }
}

// ---------------- launch ----------------
extern "C" void kernel_launch(void* const* d_in, const int* in_sizes, int n_in,
                              void* d_out, int out_size, void* d_ws, size_t ws_size,
                              hipStream_t stream) {
  const float* x     = (const float*)d_in[0];
  const float* qkv_w = (const float*)d_in[1];
  const float* out_w = (const float*)d_in[2];
  const float* out_b = (const float*)d_in[3];
  float* out = (float*)d_out;

  unsigned short* ws   = (unsigned short*)d_ws;
  unsigned short* xb   = ws;                        // 4096*1024
  unsigned short* wq   = xb  + 4096 * 1024;         // 3072*1024
  unsigned short* wo   = wq  + 3072 * 1024;         // 1024*1024
  unsigned short* Qs   = wo  + 1024 * 1024;         // 32*2048*64
  unsigned short* Ks   = Qs  + 32 * 2048 * 64;      // 32*2048*64
  unsigned short* Vts  = Ks  + 32 * 2048 * 64;      // 32*64*2048
  unsigned short* attn = Vts + 32 * 64 * 2048;      // 4096*1024

  k_cvt<<<4096, 256, 0, stream>>>(x,     xb, 4096 * 1024);
  k_cvt<<<3072, 256, 0, stream>>>(qkv_w, wq, 3072 * 1024);
  k_cvt<<<1024, 256, 0, stream>>>(out_w, wo, 1024 * 1024);
  k_qkv_gemm<<<dim3(32, 24), 256, 0, stream>>>(xb, wq, Qs, Ks, Vts);
  k_attn<<<1024, 256, 0, stream>>>(Qs, Ks, Vts, attn);
  k_out_gemm<<<dim3(32, 8), 256, 0, stream>>>(attn, wo, out_b, out);
}

// Round 12
// 242.739 us; speedup vs baseline: 1.2634x; 1.2634x over previous
//
#include <hip/hip_runtime.h>
#include <hip/hip_bf16.h>
#include <cstdint>

// Toy MultiHeadAttention: B=2, L=2048, D=1024, H=16, HD=64, causal, eval (no dropout)
// Pipeline: fp32->bf16 converts; QKV GEMM (bf16 MFMA) with Q/K/Vt scatter epilogue;
// causal flash attention (swapped-QK^T, in-register softmax + P^T transpose, no LDS);
// out GEMM + bias (fp32 out).
// == round-2 PASSING kernel (155us attn) + longest-first strip relabel ONLY ==

typedef __attribute__((ext_vector_type(8))) short sh8;    // 8 bf16 in 4 VGPRs (MFMA A/B frag)
typedef __attribute__((ext_vector_type(4))) float f32x4;  // MFMA C/D frag

__device__ __forceinline__ unsigned short f2b(float f) {  // fp32 -> bf16 RNE
  unsigned int u = __float_as_uint(f);
  u += 0x7FFFu + ((u >> 16) & 1u);
  return (unsigned short)(u >> 16);
}

__device__ __forceinline__ unsigned int pack2(float lo, float hi) {  // 2xbf16 in u32
  return (unsigned int)f2b(lo) | ((unsigned int)f2b(hi) << 16);
}

__device__ __forceinline__ void gload_lds16(const void* g, void* l) {
  __builtin_amdgcn_global_load_lds((__attribute__((address_space(1))) void*)g,
                                   (__attribute__((address_space(3))) void*)l,
                                   16, 0, 0);
}

// ---------------- fp32 -> bf16 convert (vectorized) ----------------
__global__ __launch_bounds__(256) void k_cvt(const float* __restrict__ in,
                                             unsigned short* __restrict__ out, int n) {
  int idx = (blockIdx.x * 256 + threadIdx.x) * 4;
  if (idx >= n) return;
  float4 v = *(const float4*)&in[idx];
  union { unsigned short u[4]; uint2 w; } r;
  r.u[0] = f2b(v.x); r.u[1] = f2b(v.y); r.u[2] = f2b(v.z); r.u[3] = f2b(v.w);
  *(uint2*)&out[idx] = r.w;
}

// ---------------- shared GEMM core: C[128x128] = A[M,K] * B[N,K]^T ----------------
__device__ __forceinline__ void gemm_bt_core(
    const unsigned short* __restrict__ A,   // [M][K] bf16 row-major
    const unsigned short* __restrict__ B,   // [N][K] bf16 row-major
    int K, int m0, int n0,
    unsigned short* ldsA, unsigned short* ldsB,
    f32x4 acc[4][4]) {
  const int tid  = threadIdx.x;
  const int wv   = tid >> 6;
  const int lane = tid & 63;
  const int wm = (wv >> 1) << 6;
  const int wn = (wv & 1) << 6;
  const int sr = (wv << 5) + (lane >> 3);
  const int sc = (lane & 7) << 3;
  const int fr = lane & 15;
  const int fk = (lane >> 4) << 3;

  for (int k0 = 0; k0 < K; k0 += 64) {
#pragma unroll
    for (int t = 0; t < 4; ++t) {
      int r = sr + (t << 3);
      gload_lds16(&A[(size_t)(m0 + r) * K + k0 + sc], &ldsA[r * 64 + sc]);
      gload_lds16(&B[(size_t)(n0 + r) * K + k0 + sc], &ldsB[r * 64 + sc]);
    }
    __syncthreads();
#pragma unroll
    for (int ks = 0; ks < 2; ++ks) {
      sh8 af[4], bf[4];
#pragma unroll
      for (int mt = 0; mt < 4; ++mt)
        af[mt] = *(const sh8*)&ldsA[(wm + mt * 16 + fr) * 64 + ks * 32 + fk];
#pragma unroll
      for (int nt = 0; nt < 4; ++nt)
        bf[nt] = *(const sh8*)&ldsB[(wn + nt * 16 + fr) * 64 + ks * 32 + fk];
#pragma unroll
      for (int mt = 0; mt < 4; ++mt)
#pragma unroll
        for (int nt = 0; nt < 4; ++nt)
          acc[mt][nt] = __builtin_amdgcn_mfma_f32_16x16x32_bf16(af[mt], bf[nt], acc[mt][nt], 0, 0, 0);
    }
    __syncthreads();
  }
}

// ---------------- QKV projection + scatter ----------------
__global__ __launch_bounds__(256) void k_qkv_gemm(
    const unsigned short* __restrict__ xb, const unsigned short* __restrict__ wq,
    unsigned short* __restrict__ Q, unsigned short* __restrict__ Kc,
    unsigned short* __restrict__ Vt) {
  __shared__ __align__(16) unsigned short lds[2 * 128 * 64];
  f32x4 acc[4][4];
  const f32x4 fz = {0.f, 0.f, 0.f, 0.f};
#pragma unroll
  for (int i = 0; i < 4; ++i)
#pragma unroll
    for (int j = 0; j < 4; ++j) acc[i][j] = fz;

  const int m0 = blockIdx.x * 128, n0 = blockIdx.y * 128;
  gemm_bt_core(xb, wq, 1024, m0, n0, lds, lds + 128 * 64, acc);

  const int tid = threadIdx.x, wv = tid >> 6, lane = tid & 63;
  const int wm = (wv >> 1) << 6, wn = (wv & 1) << 6;
  const int r4 = (lane >> 4) << 2, fr = lane & 15;
#pragma unroll
  for (int mt = 0; mt < 4; ++mt)
#pragma unroll
    for (int nt = 0; nt < 4; ++nt)
#pragma unroll
      for (int i = 0; i < 4; ++i) {
        int row = m0 + wm + mt * 16 + r4 + i;   // m in [0,4096)
        int col = n0 + wn + nt * 16 + fr;       // n in [0,3072)
        float v = acc[mt][nt][i];
        int b = row >> 11, lq = row & 2047;
        int which = col >> 10, rem = col & 1023;
        int h = rem >> 6, hd = rem & 63;
        size_t bh = (size_t)(b * 16 + h);
        if (which == 0)      Q [(bh * 2048 + lq) * 64 + hd] = f2b(v * 0.125f);
        else if (which == 1) Kc[(bh * 2048 + lq) * 64 + hd] = f2b(v);
        else                 Vt[(bh * 64 + hd) * 2048 + lq] = f2b(v);
      }
}

// ---------------- causal flash attention (swapped QK^T, in-register softmax) --------
// grid: 1024 blocks x 256 thr; blockIdx = quad*32 + bh (bh fastest for CU balance).
// 4 independent waves per block (no barriers, no LDS); wave handles one 16-row q-strip:
// strip = 127 - (quad*4 + wv)  [longest strips dispatched first -- ONLY change vs r2].
// Swapped QK: s = mfma(K,Q) -> lane owns q-col (q = qw + lane&15),
// kv rows = (lane>>4)*4 + i per 16-row tile. Softmax per-lane scalar + 2 shuffles.
// P^T rebuilt in registers (xor16/xor32 exchange) as PV B-frag. PV: o = mfma(Vt, P^T).
__global__ __launch_bounds__(256, 4) void k_attn(
    const unsigned short* __restrict__ Q, const unsigned short* __restrict__ Kc,
    const unsigned short* __restrict__ Vt, unsigned short* __restrict__ attn) {
  const int bh   = blockIdx.x & 31;
  const int quad = blockIdx.x >> 5;
  const int wv = threadIdx.x >> 6, lane = threadIdx.x & 63;
  const int strip = 127 - (quad * 4 + wv);   // 0..127, longest first (only delta vs r2)
  const int qw = strip << 4;
  const int b = bh >> 4, h = bh & 15;
  const unsigned short* Qb = Q  + (size_t)bh * 2048 * 64;
  const unsigned short* Kb = Kc + (size_t)bh * 2048 * 64;
  const unsigned short* Vb = Vt + (size_t)bh * 64 * 2048;
  const int fr = lane & 15, g = lane >> 4;
  const int fk = g << 3, r4 = g << 2;
  const f32x4 fz = {0.f, 0.f, 0.f, 0.f};
  const bool godd = (g & 1) != 0;
  const bool gup  = g >= 2;
  const bool gswap = godd != gup;         // g==1 || g==2

  sh8 qf[2];
#pragma unroll
  for (int ks = 0; ks < 2; ++ks)
    qf[ks] = *(const sh8*)&Qb[(size_t)(qw + fr) * 64 + ks * 32 + fk];

  f32x4 o[4];
#pragma unroll
  for (int i = 0; i < 4; ++i) o[i] = fz;
  float m_i = -1e30f, l_i = 0.f;

  const int nj = (qw + 47) >> 5;          // 32-kv tiles up to the diagonal
  for (int j = 0; j < nj; ++j) {
    const int kvb = j << 5;
    // QK^T swapped: s[t] row = kv (r4+i), col = q (fr)
    f32x4 s[2]; s[0] = fz; s[1] = fz;
#pragma unroll
    for (int t = 0; t < 2; ++t)
#pragma unroll
      for (int ks = 0; ks < 2; ++ks) {
        sh8 kf = *(const sh8*)&Kb[(size_t)(kvb + t * 16 + fr) * 64 + ks * 32 + fk];
        s[t] = __builtin_amdgcn_mfma_f32_16x16x32_bf16(kf, qf[ks], s[t], 0, 0, 0);
      }
    // hoist V loads (independent of softmax) for latency overlap
    sh8 vf[4];
#pragma unroll
    for (int hb = 0; hb < 4; ++hb)
      vf[hb] = *(const sh8*)&Vb[(size_t)(hb * 16 + fr) * 2048 + kvb + fk];

    if (j == nj - 1) {  // diagonal tile: causal mask (kv > q)
#pragma unroll
      for (int t = 0; t < 2; ++t)
#pragma unroll
        for (int i = 0; i < 4; ++i)
          if (kvb + t * 16 + r4 + i > qw + fr) s[t][i] = -1e30f;
    }
    // per-lane softmax for q = qw+fr: within-lane 8-value reduce + xor16 + xor32
    float mx = fmaxf(fmaxf(fmaxf(s[0][0], s[0][1]), fmaxf(s[0][2], s[0][3])),
                     fmaxf(fmaxf(s[1][0], s[1][1]), fmaxf(s[1][2], s[1][3])));
    mx = fmaxf(mx, __shfl_xor(mx, 16, 64));
    mx = fmaxf(mx, __shfl_xor(mx, 32, 64));
    const float mn = fmaxf(m_i, mx);
    const float scale = __expf(m_i - mn);
    m_i = mn;
    float p0[4], p1[4];
#pragma unroll
    for (int i = 0; i < 4; ++i) {
      p0[i] = __expf(s[0][i] - mn);
      p1[i] = __expf(s[1][i] - mn);
    }
    float rs = (p0[0] + p0[1]) + (p0[2] + p0[3]) + (p1[0] + p1[1]) + (p1[2] + p1[3]);
    rs += __shfl_xor(rs, 16, 64);
    rs += __shfl_xor(rs, 32, 64);
    l_i = l_i * scale + rs;
#pragma unroll
    for (int hb = 0; hb < 4; ++hb)
#pragma unroll
      for (int i = 0; i < 4; ++i) o[hb][i] *= scale;

    // ---- build P^T B-frag in registers: lane needs kv = kvb + 8g..8g+7 at col q=fr ----
    unsigned int P0L = pack2(p0[0], p0[1]);   // kv {4g,   4g+1} (t0)
    unsigned int P0H = pack2(p0[2], p0[3]);   // kv {4g+2, 4g+3} (t0)
    unsigned int P1L = pack2(p1[0], p1[1]);   // kv {16+4g, 16+4g+1} (t1)
    unsigned int P1H = pack2(p1[2], p1[3]);   // kv {16+4g+2, 16+4g+3} (t1)
    // xor16: merge pair (g & ~1, g | 1) into 8-kv blocks
    unsigned int x0 = __shfl_xor((int)P0L, 16, 64);
    unsigned int x1 = __shfl_xor((int)P0H, 16, 64);
    unsigned int y0 = __shfl_xor((int)P1L, 16, 64);
    unsigned int y1 = __shfl_xor((int)P1H, 16, 64);
    unsigned int A0 = godd ? x0 : P0L, A1 = godd ? x1 : P0H;
    unsigned int A2 = godd ? P0L : x0, A3 = godd ? P0H : x1;   // t0 block of own pair
    unsigned int B0 = godd ? y0 : P1L, B1 = godd ? y1 : P1H;
    unsigned int B2 = godd ? P1L : y0, B3 = godd ? P1H : y1;   // t1 block of own pair
    // xor32: fetch the other pair's blocks
    unsigned int As0 = __shfl_xor((int)A0, 32, 64), As1 = __shfl_xor((int)A1, 32, 64);
    unsigned int As2 = __shfl_xor((int)A2, 32, 64), As3 = __shfl_xor((int)A3, 32, 64);
    unsigned int Bs0 = __shfl_xor((int)B0, 32, 64), Bs1 = __shfl_xor((int)B1, 32, 64);
    unsigned int Bs2 = __shfl_xor((int)B2, 32, 64), Bs3 = __shfl_xor((int)B3, 32, 64);
    // g0 -> A, g1 -> As, g2 -> Bs, g3 -> B
    union { unsigned int w[4]; sh8 v; } fu;
    fu.w[0] = gswap ? (gup ? Bs0 : As0) : (gup ? B0 : A0);
    fu.w[1] = gswap ? (gup ? Bs1 : As1) : (gup ? B1 : A1);
    fu.w[2] = gswap ? (gup ? Bs2 : As2) : (gup ? B2 : A2);
    fu.w[3] = gswap ? (gup ? Bs3 : As3) : (gup ? B3 : A3);

#pragma unroll
    for (int hb = 0; hb < 4; ++hb)
      o[hb] = __builtin_amdgcn_mfma_f32_16x16x32_bf16(vf[hb], fu.v, o[hb], 0, 0, 0);
  }

  const float inv = 1.0f / l_i;
  // o layout: col = q = fr (lane), row = d = hb*16 + r4 + i -> pack i-pairs, b32 stores
  const size_t base = ((size_t)(b * 2048 + qw + fr)) * 1024 + h * 64;
#pragma unroll
  for (int hb = 0; hb < 4; ++hb)
#pragma unroll
    for (int i2 = 0; i2 < 2; ++i2) {
      unsigned int pw = pack2(o[hb][2 * i2] * inv, o[hb][2 * i2 + 1] * inv);
      *(unsigned int*)&attn[base + hb * 16 + r4 + 2 * i2] = pw;
    }
}

// ---------------- output projection + bias (fp32 out) ----------------
__global__ __launch_bounds__(256) void k_out_gemm(
    const unsigned short* __restrict__ attn, const unsigned short* __restrict__ wo,
    const float* __restrict__ bias, float* __restrict__ out) {
  __shared__ __align__(16) unsigned short lds[2 * 128 * 64];
  f32x4 acc[4][4];
  const f32x4 fz = {0.f, 0.f, 0.f, 0.f};
#pragma unroll
  for (int i = 0; i < 4; ++i)
#pragma unroll
    for (int j = 0; j < 4; ++j) acc[i][j] = fz;

  const int m0 = blockIdx.x * 128, n0 = blockIdx.y * 128;
  gemm_bt_core(attn, wo, 1024, m0, n0, lds, lds + 128 * 64, acc);

  const int tid = threadIdx.x, wv = tid >> 6, lane = tid & 63;
  const int wm = (wv >> 1) << 6, wn = (wv & 1) << 6;
  const int r4 = (lane >> 4) << 2, fr = lane & 15;
#pragma unroll
  for (int mt = 0; mt < 4; ++mt)
#pragma unroll
    for (int nt = 0; nt < 4; ++nt)
#pragma unroll
      for (int i = 0; i < 4; ++i) {
        int row = m0 + wm + mt * 16 + r4 + i;
        int col = n0 + wn + nt * 16 + fr;
        out[(size_t)row * 1024 + col] = acc[mt][nt][i] + bias[col];
      }
}

// ---------------- launch ----------------
extern "C" void kernel_launch(void* const* d_in, const int* in_sizes, int n_in,
                              void* d_out, int out_size, void* d_ws, size_t ws_size,
                              hipStream_t stream) {
  const float* x     = (const float*)d_in[0];
  const float* qkv_w = (const float*)d_in[1];
  const float* out_w = (const float*)d_in[2];
  const float* out_b = (const float*)d_in[3];
  float* out = (float*)d_out;

  unsigned short* ws   = (unsigned short*)d_ws;
  unsigned short* xb   = ws;                        // 4096*1024
  unsigned short* wq   = xb  + 4096 * 1024;         // 3072*1024
  unsigned short* wo   = wq  + 3072 * 1024;         // 1024*1024
  unsigned short* Qs   = wo  + 1024 * 1024;         // 32*2048*64
  unsigned short* Ks   = Qs  + 32 * 2048 * 64;      // 32*2048*64
  unsigned short* Vts  = Ks  + 32 * 2048 * 64;      // 32*64*2048
  unsigned short* attn = Vts + 32 * 64 * 2048;      // 4096*1024

  k_cvt<<<4096, 256, 0, stream>>>(x,     xb, 4096 * 1024);
  k_cvt<<<3072, 256, 0, stream>>>(qkv_w, wq, 3072 * 1024);
  k_cvt<<<1024, 256, 0, stream>>>(out_w, wo, 1024 * 1024);
  k_qkv_gemm<<<dim3(32, 24), 256, 0, stream>>>(xb, wq, Qs, Ks, Vts);
  k_attn<<<1024, 256, 0, stream>>>(Qs, Ks, Vts, attn);
  k_out_gemm<<<dim3(32, 8), 256, 0, stream>>>(attn, wo, out_b, out);
}

// Round 13
// 218.161 us; speedup vs baseline: 1.4057x; 1.1127x over previous
//
#include <hip/hip_runtime.h>
#include <hip/hip_bf16.h>
#include <cstdint>

// Toy MultiHeadAttention: B=2, L=2048, D=1024, H=16, HD=64, causal, eval (no dropout)
// Pipeline: fp32->bf16 converts; QKV GEMM (bf16 MFMA) with Q/K/Vt scatter epilogue;
// causal flash attention: r2-PASSING per-tile math, kv range split across the
// block's 4 waves (flash-decode style) + LDS merge -> 4x wave-level parallelism;
// out GEMM + bias (fp32 out).

typedef __attribute__((ext_vector_type(8))) short sh8;    // 8 bf16 in 4 VGPRs (MFMA A/B frag)
typedef __attribute__((ext_vector_type(4))) float f32x4;  // MFMA C/D frag

__device__ __forceinline__ unsigned short f2b(float f) {  // fp32 -> bf16 RNE
  unsigned int u = __float_as_uint(f);
  u += 0x7FFFu + ((u >> 16) & 1u);
  return (unsigned short)(u >> 16);
}

__device__ __forceinline__ unsigned int pack2(float lo, float hi) {  // 2xbf16 in u32
  return (unsigned int)f2b(lo) | ((unsigned int)f2b(hi) << 16);
}

__device__ __forceinline__ void gload_lds16(const void* g, void* l) {
  __builtin_amdgcn_global_load_lds((__attribute__((address_space(1))) void*)g,
                                   (__attribute__((address_space(3))) void*)l,
                                   16, 0, 0);
}

// ---------------- fp32 -> bf16 convert (vectorized) ----------------
__global__ __launch_bounds__(256) void k_cvt(const float* __restrict__ in,
                                             unsigned short* __restrict__ out, int n) {
  int idx = (blockIdx.x * 256 + threadIdx.x) * 4;
  if (idx >= n) return;
  float4 v = *(const float4*)&in[idx];
  union { unsigned short u[4]; uint2 w; } r;
  r.u[0] = f2b(v.x); r.u[1] = f2b(v.y); r.u[2] = f2b(v.z); r.u[3] = f2b(v.w);
  *(uint2*)&out[idx] = r.w;
}

// ---------------- shared GEMM core: C[128x128] = A[M,K] * B[N,K]^T ----------------
__device__ __forceinline__ void gemm_bt_core(
    const unsigned short* __restrict__ A,   // [M][K] bf16 row-major
    const unsigned short* __restrict__ B,   // [N][K] bf16 row-major
    int K, int m0, int n0,
    unsigned short* ldsA, unsigned short* ldsB,
    f32x4 acc[4][4]) {
  const int tid  = threadIdx.x;
  const int wv   = tid >> 6;
  const int lane = tid & 63;
  const int wm = (wv >> 1) << 6;
  const int wn = (wv & 1) << 6;
  const int sr = (wv << 5) + (lane >> 3);
  const int sc = (lane & 7) << 3;
  const int fr = lane & 15;
  const int fk = (lane >> 4) << 3;

  for (int k0 = 0; k0 < K; k0 += 64) {
#pragma unroll
    for (int t = 0; t < 4; ++t) {
      int r = sr + (t << 3);
      gload_lds16(&A[(size_t)(m0 + r) * K + k0 + sc], &ldsA[r * 64 + sc]);
      gload_lds16(&B[(size_t)(n0 + r) * K + k0 + sc], &ldsB[r * 64 + sc]);
    }
    __syncthreads();
#pragma unroll
    for (int ks = 0; ks < 2; ++ks) {
      sh8 af[4], bf[4];
#pragma unroll
      for (int mt = 0; mt < 4; ++mt)
        af[mt] = *(const sh8*)&ldsA[(wm + mt * 16 + fr) * 64 + ks * 32 + fk];
#pragma unroll
      for (int nt = 0; nt < 4; ++nt)
        bf[nt] = *(const sh8*)&ldsB[(wn + nt * 16 + fr) * 64 + ks * 32 + fk];
#pragma unroll
      for (int mt = 0; mt < 4; ++mt)
#pragma unroll
        for (int nt = 0; nt < 4; ++nt)
          acc[mt][nt] = __builtin_amdgcn_mfma_f32_16x16x32_bf16(af[mt], bf[nt], acc[mt][nt], 0, 0, 0);
    }
    __syncthreads();
  }
}

// ---------------- QKV projection + scatter ----------------
__global__ __launch_bounds__(256) void k_qkv_gemm(
    const unsigned short* __restrict__ xb, const unsigned short* __restrict__ wq,
    unsigned short* __restrict__ Q, unsigned short* __restrict__ Kc,
    unsigned short* __restrict__ Vt) {
  __shared__ __align__(16) unsigned short lds[2 * 128 * 64];
  f32x4 acc[4][4];
  const f32x4 fz = {0.f, 0.f, 0.f, 0.f};
#pragma unroll
  for (int i = 0; i < 4; ++i)
#pragma unroll
    for (int j = 0; j < 4; ++j) acc[i][j] = fz;

  const int m0 = blockIdx.x * 128, n0 = blockIdx.y * 128;
  gemm_bt_core(xb, wq, 1024, m0, n0, lds, lds + 128 * 64, acc);

  const int tid = threadIdx.x, wv = tid >> 6, lane = tid & 63;
  const int wm = (wv >> 1) << 6, wn = (wv & 1) << 6;
  const int r4 = (lane >> 4) << 2, fr = lane & 15;
#pragma unroll
  for (int mt = 0; mt < 4; ++mt)
#pragma unroll
    for (int nt = 0; nt < 4; ++nt)
#pragma unroll
      for (int i = 0; i < 4; ++i) {
        int row = m0 + wm + mt * 16 + r4 + i;   // m in [0,4096)
        int col = n0 + wn + nt * 16 + fr;       // n in [0,3072)
        float v = acc[mt][nt][i];
        int b = row >> 11, lq = row & 2047;
        int which = col >> 10, rem = col & 1023;
        int h = rem >> 6, hd = rem & 63;
        size_t bh = (size_t)(b * 16 + h);
        if (which == 0)      Q [(bh * 2048 + lq) * 64 + hd] = f2b(v * 0.125f);
        else if (which == 1) Kc[(bh * 2048 + lq) * 64 + hd] = f2b(v);
        else                 Vt[(bh * 64 + hd) * 2048 + lq] = f2b(v);
      }
}

// ---------------- causal flash attention (kv-split, r2 math per chunk) ----------------
// grid: 4096 blocks x 256 thr; blockIdx = sIdx*32 + bh; strip = 127 - sIdx (longest
// first, bh fastest). ALL 4 waves work on the SAME 16-row strip; wave wv processes
// kv-tiles [nj*wv/4, nj*(wv+1)/4) with the UNMODIFIED r2 loop (swapped QK^T,
// per-lane softmax + xor16/xor32 reduce, register P^T transpose, x32-MFMA PV).
// Partials (o, m, l) merged in LDS: m*=max_c m_c; o*=sum o_c*e^(m_c-m*); same l.
__global__ __launch_bounds__(256, 4) void k_attn(
    const unsigned short* __restrict__ Q, const unsigned short* __restrict__ Kc,
    const unsigned short* __restrict__ Vt, unsigned short* __restrict__ attn) {
  __shared__ float lds_o[4][64][17];   // [wave][d][q], stride 17 (pad)
  __shared__ float lds_m[4][16], lds_l[4][16];

  const int bh   = blockIdx.x & 31;
  const int strip = 127 - (blockIdx.x >> 5);   // 0..127, longest first
  const int wv = threadIdx.x >> 6, lane = threadIdx.x & 63;
  const int qw = strip << 4;
  const int b = bh >> 4, h = bh & 15;
  const unsigned short* Qb = Q  + (size_t)bh * 2048 * 64;
  const unsigned short* Kb = Kc + (size_t)bh * 2048 * 64;
  const unsigned short* Vb = Vt + (size_t)bh * 64 * 2048;
  const int fr = lane & 15, g = lane >> 4;
  const int fk = g << 3, r4 = g << 2;
  const f32x4 fz = {0.f, 0.f, 0.f, 0.f};
  const bool godd = (g & 1) != 0;
  const bool gup  = g >= 2;
  const bool gswap = godd != gup;         // g==1 || g==2

  sh8 qf[2];
#pragma unroll
  for (int ks = 0; ks < 2; ++ks)
    qf[ks] = *(const sh8*)&Qb[(size_t)(qw + fr) * 64 + ks * 32 + fk];

  f32x4 o[4];
#pragma unroll
  for (int i = 0; i < 4; ++i) o[i] = fz;
  float m_i = -1e30f, l_i = 0.f;

  const int nj = (qw + 47) >> 5;          // 32-kv tiles up to the diagonal
  const int j0 = (nj * wv) >> 2;          // this wave's chunk
  const int j1 = (nj * (wv + 1)) >> 2;
  for (int j = j0; j < j1; ++j) {
    const int kvb = j << 5;
    // QK^T swapped: s[t] row = kv (r4+i), col = q (fr)
    f32x4 s[2]; s[0] = fz; s[1] = fz;
#pragma unroll
    for (int t = 0; t < 2; ++t)
#pragma unroll
      for (int ks = 0; ks < 2; ++ks) {
        sh8 kf = *(const sh8*)&Kb[(size_t)(kvb + t * 16 + fr) * 64 + ks * 32 + fk];
        s[t] = __builtin_amdgcn_mfma_f32_16x16x32_bf16(kf, qf[ks], s[t], 0, 0, 0);
      }
    // hoist V loads (independent of softmax) for latency overlap
    sh8 vf[4];
#pragma unroll
    for (int hb = 0; hb < 4; ++hb)
      vf[hb] = *(const sh8*)&Vb[(size_t)(hb * 16 + fr) * 2048 + kvb + fk];

    if (j == nj - 1) {  // diagonal tile: causal mask (kv > q)
#pragma unroll
      for (int t = 0; t < 2; ++t)
#pragma unroll
        for (int i = 0; i < 4; ++i)
          if (kvb + t * 16 + r4 + i > qw + fr) s[t][i] = -1e30f;
    }
    // per-lane softmax for q = qw+fr: within-lane 8-value reduce + xor16 + xor32
    float mx = fmaxf(fmaxf(fmaxf(s[0][0], s[0][1]), fmaxf(s[0][2], s[0][3])),
                     fmaxf(fmaxf(s[1][0], s[1][1]), fmaxf(s[1][2], s[1][3])));
    mx = fmaxf(mx, __shfl_xor(mx, 16, 64));
    mx = fmaxf(mx, __shfl_xor(mx, 32, 64));
    const float mn = fmaxf(m_i, mx);
    const float scale = __expf(m_i - mn);
    m_i = mn;
    float p0[4], p1[4];
#pragma unroll
    for (int i = 0; i < 4; ++i) {
      p0[i] = __expf(s[0][i] - mn);
      p1[i] = __expf(s[1][i] - mn);
    }
    float rs = (p0[0] + p0[1]) + (p0[2] + p0[3]) + (p1[0] + p1[1]) + (p1[2] + p1[3]);
    rs += __shfl_xor(rs, 16, 64);
    rs += __shfl_xor(rs, 32, 64);
    l_i = l_i * scale + rs;
#pragma unroll
    for (int hb = 0; hb < 4; ++hb)
#pragma unroll
      for (int i = 0; i < 4; ++i) o[hb][i] *= scale;

    // ---- build P^T B-frag in registers: lane needs kv = kvb + 8g..8g+7 at col q=fr ----
    unsigned int P0L = pack2(p0[0], p0[1]);   // kv {4g,   4g+1} (t0)
    unsigned int P0H = pack2(p0[2], p0[3]);   // kv {4g+2, 4g+3} (t0)
    unsigned int P1L = pack2(p1[0], p1[1]);   // kv {16+4g, 16+4g+1} (t1)
    unsigned int P1H = pack2(p1[2], p1[3]);   // kv {16+4g+2, 16+4g+3} (t1)
    // xor16: merge pair (g & ~1, g | 1) into 8-kv blocks
    unsigned int x0 = __shfl_xor((int)P0L, 16, 64);
    unsigned int x1 = __shfl_xor((int)P0H, 16, 64);
    unsigned int y0 = __shfl_xor((int)P1L, 16, 64);
    unsigned int y1 = __shfl_xor((int)P1H, 16, 64);
    unsigned int A0 = godd ? x0 : P0L, A1 = godd ? x1 : P0H;
    unsigned int A2 = godd ? P0L : x0, A3 = godd ? P0H : x1;   // t0 block of own pair
    unsigned int B0 = godd ? y0 : P1L, B1 = godd ? y1 : P1H;
    unsigned int B2 = godd ? P1L : y0, B3 = godd ? P1H : y1;   // t1 block of own pair
    // xor32: fetch the other pair's blocks
    unsigned int As0 = __shfl_xor((int)A0, 32, 64), As1 = __shfl_xor((int)A1, 32, 64);
    unsigned int As2 = __shfl_xor((int)A2, 32, 64), As3 = __shfl_xor((int)A3, 32, 64);
    unsigned int Bs0 = __shfl_xor((int)B0, 32, 64), Bs1 = __shfl_xor((int)B1, 32, 64);
    unsigned int Bs2 = __shfl_xor((int)B2, 32, 64), Bs3 = __shfl_xor((int)B3, 32, 64);
    // g0 -> A, g1 -> As, g2 -> Bs, g3 -> B
    union { unsigned int w[4]; sh8 v; } fu;
    fu.w[0] = gswap ? (gup ? Bs0 : As0) : (gup ? B0 : A0);
    fu.w[1] = gswap ? (gup ? Bs1 : As1) : (gup ? B1 : A1);
    fu.w[2] = gswap ? (gup ? Bs2 : As2) : (gup ? B2 : A2);
    fu.w[3] = gswap ? (gup ? Bs3 : As3) : (gup ? B3 : A3);

#pragma unroll
    for (int hb = 0; hb < 4; ++hb)
      o[hb] = __builtin_amdgcn_mfma_f32_16x16x32_bf16(vf[hb], fu.v, o[hb], 0, 0, 0);
  }

  // ---- merge the 4 waves' partials (flash-decode combine) ----
#pragma unroll
  for (int hb = 0; hb < 4; ++hb)
#pragma unroll
    for (int i = 0; i < 4; ++i)
      lds_o[wv][hb * 16 + r4 + i][fr] = o[hb][i];
  if (g == 0) { lds_m[wv][fr] = m_i; lds_l[wv][fr] = l_i; }
  __syncthreads();

  // wave wv merges d-block hb = wv: d = wv*16 + 4g + i, q = qw + fr
  float mm = fmaxf(fmaxf(lds_m[0][fr], lds_m[1][fr]),
                   fmaxf(lds_m[2][fr], lds_m[3][fr]));
  float sc0 = __expf(lds_m[0][fr] - mm), sc1 = __expf(lds_m[1][fr] - mm);
  float sc2 = __expf(lds_m[2][fr] - mm), sc3 = __expf(lds_m[3][fr] - mm);
  float lt = lds_l[0][fr] * sc0 + lds_l[1][fr] * sc1
           + lds_l[2][fr] * sc2 + lds_l[3][fr] * sc3;
  const float inv = 1.0f / lt;
  const int dbase = wv * 16 + r4;
  float od[4];
#pragma unroll
  for (int i = 0; i < 4; ++i) {
    od[i] = (lds_o[0][dbase + i][fr] * sc0 + lds_o[1][dbase + i][fr] * sc1 +
             lds_o[2][dbase + i][fr] * sc2 + lds_o[3][dbase + i][fr] * sc3) * inv;
  }
  // store: row q = qw+fr, cols h*64 + dbase + {0..3} -> two b32 stores
  const size_t base = ((size_t)(b * 2048 + qw + fr)) * 1024 + h * 64 + dbase;
  *(unsigned int*)&attn[base]     = pack2(od[0], od[1]);
  *(unsigned int*)&attn[base + 2] = pack2(od[2], od[3]);
}

// ---------------- output projection + bias (fp32 out) ----------------
__global__ __launch_bounds__(256) void k_out_gemm(
    const unsigned short* __restrict__ attn, const unsigned short* __restrict__ wo,
    const float* __restrict__ bias, float* __restrict__ out) {
  __shared__ __align__(16) unsigned short lds[2 * 128 * 64];
  f32x4 acc[4][4];
  const f32x4 fz = {0.f, 0.f, 0.f, 0.f};
#pragma unroll
  for (int i = 0; i < 4; ++i)
#pragma unroll
    for (int j = 0; j < 4; ++j) acc[i][j] = fz;

  const int m0 = blockIdx.x * 128, n0 = blockIdx.y * 128;
  gemm_bt_core(attn, wo, 1024, m0, n0, lds, lds + 128 * 64, acc);

  const int tid = threadIdx.x, wv = tid >> 6, lane = tid & 63;
  const int wm = (wv >> 1) << 6, wn = (wv & 1) << 6;
  const int r4 = (lane >> 4) << 2, fr = lane & 15;
#pragma unroll
  for (int mt = 0; mt < 4; ++mt)
#pragma unroll
    for (int nt = 0; nt < 4; ++nt)
#pragma unroll
      for (int i = 0; i < 4; ++i) {
        int row = m0 + wm + mt * 16 + r4 + i;
        int col = n0 + wn + nt * 16 + fr;
        out[(size_t)row * 1024 + col] = acc[mt][nt][i] + bias[col];
      }
}

// ---------------- launch ----------------
extern "C" void kernel_launch(void* const* d_in, const int* in_sizes, int n_in,
                              void* d_out, int out_size, void* d_ws, size_t ws_size,
                              hipStream_t stream) {
  const float* x     = (const float*)d_in[0];
  const float* qkv_w = (const float*)d_in[1];
  const float* out_w = (const float*)d_in[2];
  const float* out_b = (const float*)d_in[3];
  float* out = (float*)d_out;

  unsigned short* ws   = (unsigned short*)d_ws;
  unsigned short* xb   = ws;                        // 4096*1024
  unsigned short* wq   = xb  + 4096 * 1024;         // 3072*1024
  unsigned short* wo   = wq  + 3072 * 1024;         // 1024*1024
  unsigned short* Qs   = wo  + 1024 * 1024;         // 32*2048*64
  unsigned short* Ks   = Qs  + 32 * 2048 * 64;      // 32*2048*64
  unsigned short* Vts  = Ks  + 32 * 2048 * 64;      // 32*64*2048
  unsigned short* attn = Vts + 32 * 64 * 2048;      // 4096*1024

  k_cvt<<<4096, 256, 0, stream>>>(x,     xb, 4096 * 1024);
  k_cvt<<<3072, 256, 0, stream>>>(qkv_w, wq, 3072 * 1024);
  k_cvt<<<1024, 256, 0, stream>>>(out_w, wo, 1024 * 1024);
  k_qkv_gemm<<<dim3(32, 24), 256, 0, stream>>>(xb, wq, Qs, Ks, Vts);
  k_attn<<<4096, 256, 0, stream>>>(Qs, Ks, Vts, attn);
  k_out_gemm<<<dim3(32, 8), 256, 0, stream>>>(attn, wo, out_b, out);
}